// Round 10
// baseline (271.059 us; speedup 1.0000x reference)
//
#include <hip/hip_runtime.h>

#define HALF 128
#define NMAT 16384   // 128*128
#define NTOK 131072  // 32*4096

typedef float f4 __attribute__((ext_vector_type(4)));

// N[r][c] for N = I + A/2, A = tril(X) - tril(X)^T  (identical math/order to
// the verified kernels' reg-init).
__device__ __forceinline__ float nval(const float* __restrict__ X, int r, int c) {
    int mx = r > c ? r : c;
    int mn = r ^ c ^ mx;
    float x = X[mx * HALF + mn];
    return (r == c) ? 1.0f : (r > c ? 0.5f * x : -0.5f * x);
}

// wave-0 16x16 shuffle-GJ (verbatim instruction order from verified kernels).
__device__ __forceinline__ void gj16(const float (*Rs)[132], int kcol,
                                     float (*Dc)[17], int t) {
    const int cp = t & 15, q4 = t >> 4;
    float dd[4];
    #pragma unroll
    for (int i = 0; i < 4; ++i) dd[i] = Rs[q4 * 4 + i][kcol + cp];
    #pragma unroll
    for (int k = 0; k < 16; ++k) {
        float cv[4];
        #pragma unroll
        for (int i = 0; i < 4; ++i) cv[i] = __shfl(dd[i], (q4 << 4) | k);
        float rv   = __shfl(dd[k & 3], ((k >> 2) << 4) | cp);
        float dkk  = __shfl(rv, k);
        float dinv = 1.0f / dkk;
        float sv   = rv * dinv;
        bool  own  = (cp == k);
        float rf   = own ? dinv : sv;
        #pragma unroll
        for (int i = 0; i < 4; ++i)
            dd[i] = own ? (-dd[i] * dinv) : fmaf(-cv[i], sv, dd[i]);
        dd[k & 3] = (q4 == (k >> 2)) ? rf : dd[k & 3];
    }
    #pragma unroll
    for (int i = 0; i < 4; ++i) Dc[cp][q4 * 4 + i] = dd[i];
}

// RB[m][c] = (Dinv*R)[m][c], Dinv copied into panel cols (verbatim order).
__device__ __forceinline__ void rb_build(float (*RB)[132], const float (*Rs)[132],
                                         const float (*Dc)[17], int kcol, int t) {
    const int m  = t >> 4;
    const int c0 = (t & 15) << 3;
    if (c0 == kcol || c0 == kcol + 8) {
        #pragma unroll
        for (int u = 0; u < 8; ++u) RB[m][c0 + u] = Dc[c0 + u - kcol][m];
    } else {
        float acc[8] = {0.f,0.f,0.f,0.f,0.f,0.f,0.f,0.f};
        #pragma unroll
        for (int j = 0; j < 16; ++j) {           // j ascending (verbatim)
            float dj = Dc[j][m];
            #pragma unroll
            for (int u = 0; u < 8; ++u)
                acc[u] = fmaf(dj, Rs[j][c0 + u], acc[u]);
        }
        *(float4*)&RB[m][c0]     = make_float4(acc[0], acc[1], acc[2], acc[3]);
        *(float4*)&RB[m][c0 + 4] = make_float4(acc[4], acc[5], acc[6], acc[7]);
    }
}

// rank-16 update of a 16-row LDS block in place (non-K rows; verbatim order).
__device__ __forceinline__ void adv(float (*A)[132], const float (*Cm)[17],
                                    const float (*RB)[132], int kcol, int t) {
    const int j  = t >> 4;
    const int c0 = (t & 15) << 3;
    const bool pan = (c0 == kcol) || (c0 == kcol + 8);
    float w[8];
    if (pan) {
        #pragma unroll
        for (int u = 0; u < 8; ++u) w[u] = 0.0f;
    } else {
        #pragma unroll
        for (int u = 0; u < 8; ++u) w[u] = A[j][c0 + u];
    }
    #pragma unroll
    for (int m = 0; m < 16; ++m) {               // m ascending (verbatim)
        float cm = Cm[j][m];
        #pragma unroll
        for (int u = 0; u < 8; ++u)
            w[u] = fmaf(-cm, RB[m][c0 + u], w[u]);
    }
    #pragma unroll
    for (int u = 0; u < 8; ++u) A[j][c0 + u] = w[u];
}

// ---------------------------------------------------------------------------
// K1 (round-10): TWO GJ block-steps per kernel -> 4 dispatches (was 8).
// The cross-block dependency (next step's panel rows K') is removed by
// redundantly advancing the 16 K'-rows through step S0 in LDS (128 fma/thr,
// far cheaper than the ~4.7us dispatch boundary measured in rounds 8/9).
// Own rows advance in LDS Wt between the two steps.  Blocks read only Win
// and write disjoint Wout rows -> race-free.  All fma sequences verbatim
// from the round-9 passing kernel -> bit-identical output.
// ---------------------------------------------------------------------------
template<int S0, bool FIRST, bool LAST>
__global__ __launch_bounds__(256) void k1_2step(const float* __restrict__ prim,
                                                const float* __restrict__ Win,
                                                float* __restrict__ Wout) {
    __shared__ __align__(16) float R1[16][132];   // pre-S0 rows K
    __shared__ __align__(16) float R2[16][132];   // rows K' (pre-S0 -> post-S0)
    __shared__ __align__(16) float RB1[16][132];
    __shared__ __align__(16) float RB2[16][132];
    __shared__ __align__(16) float Wt[16][132];   // own rows (pre -> post-S0)
    __shared__ float Dc1[16][17];
    __shared__ float Dc2[16][17];
    __shared__ float C1[16][17];                  // own-rows C-slice (step S0)
    __shared__ float C2[16][17];                  // K'-rows C-slice (step S0)

    constexpr int k0 = S0 << 4;
    constexpr int k1 = (S0 + 1) << 4;
    const int blk = blockIdx.x;
    const int b   = blk >> 3;            // matrix
    const int rg  = blk & 7;             // own row-group: rows r0..r0+15
    const int r0  = rg << 4;
    const int t   = threadIdx.x;
    const float* __restrict__ X  = prim + b * NMAT;
    const float* __restrict__ Wi = Win  + b * NMAT;
    float*       __restrict__ Wo = Wout + b * NMAT;

    {   // ---- stage everything (pre-S0 values)
        const int j  = t >> 4;
        const int c0 = (t & 15) << 3;
        if (FIRST) {
            #pragma unroll
            for (int u = 0; u < 8; ++u) {
                R1[j][c0 + u] = nval(X, k0 + j, c0 + u);
                R2[j][c0 + u] = nval(X, k1 + j, c0 + u);
                Wt[j][c0 + u] = nval(X, r0 + j, c0 + u);
            }
            C1[j][t & 15] = nval(X, r0 + j, k0 + (t & 15));
            C2[j][t & 15] = nval(X, k1 + j, k0 + (t & 15));
        } else {
            *(float4*)&R1[j][c0]     = *(const float4*)&Wi[(k0 + j) * HALF + c0];
            *(float4*)&R1[j][c0 + 4] = *(const float4*)&Wi[(k0 + j) * HALF + c0 + 4];
            *(float4*)&R2[j][c0]     = *(const float4*)&Wi[(k1 + j) * HALF + c0];
            *(float4*)&R2[j][c0 + 4] = *(const float4*)&Wi[(k1 + j) * HALF + c0 + 4];
            *(float4*)&Wt[j][c0]     = *(const float4*)&Wi[(r0 + j) * HALF + c0];
            *(float4*)&Wt[j][c0 + 4] = *(const float4*)&Wi[(r0 + j) * HALF + c0 + 4];
            C1[j][t & 15] = Wi[(r0 + j) * HALF + k0 + (t & 15)];
            C2[j][t & 15] = Wi[(k1 + j) * HALF + k0 + (t & 15)];
        }
    }
    __syncthreads();

    // ---- step S0: GJ + RB1
    if (t < 64) gj16(R1, k0, Dc1, t);
    __syncthreads();
    rb_build(RB1, R1, Dc1, k0, t);
    __syncthreads();

    // ---- advance own rows and K'-rows through step S0 (in LDS)
    {
        const int j  = t >> 4;
        const int c0 = (t & 15) << 3;
        if (rg == S0) {                          // own rows are K: W[K,:] = RB1
            #pragma unroll
            for (int u = 0; u < 8; ++u) Wt[j][c0 + u] = RB1[j][c0 + u];
        } else {
            adv(Wt, C1, RB1, k0, t);
        }
        adv(R2, C2, RB1, k0, t);                 // K' rows (K' != K always)
    }
    __syncthreads();

    // ---- step S0+1: GJ + RB2 from post-S0 K' rows
    if (t < 64) gj16(R2, k1, Dc2, t);
    __syncthreads();
    rb_build(RB2, R2, Dc2, k1, t);
    __syncthreads();

    // ---- final own-row update (step S0+1), write Wout
    {
        const int rr = t >> 4;
        const int r  = r0 + rr;
        const int c0 = (t & 15) << 3;
        float w[8];
        if (rg == S0 + 1) {                      // own rows are K': W = RB2
            #pragma unroll
            for (int u = 0; u < 8; ++u) w[u] = RB2[rr][c0 + u];
        } else {
            const bool pan = (c0 == k1) || (c0 == k1 + 8);
            if (pan) {
                #pragma unroll
                for (int u = 0; u < 8; ++u) w[u] = 0.0f;
            } else {
                #pragma unroll
                for (int u = 0; u < 8; ++u) w[u] = Wt[rr][c0 + u];
            }
            #pragma unroll
            for (int m = 0; m < 16; ++m) {       // m ascending (verbatim)
                float cm = Wt[rr][k1 + m];       // post-S0 own C-slice
                #pragma unroll
                for (int u = 0; u < 8; ++u)
                    w[u] = fmaf(-cm, RB2[m][c0 + u], w[u]);
            }
        }
        if (LAST) {
            #pragma unroll
            for (int u = 0; u < 8; ++u)
                w[u] = 2.0f * w[u] - ((r == c0 + u) ? 1.0f : 0.0f);
        }
        *(float4*)&Wo[r * HALF + c0]     = make_float4(w[0], w[1], w[2], w[3]);
        *(float4*)&Wo[r * HALF + c0 + 4] = make_float4(w[4], w[5], w[6], w[7]);
    }
}

// ---------------------------------------------------------------------------
// K2a: rows [0,256) from identity, steps d=0..6.  ROUND-2 VERIFIED FORM.
// ---------------------------------------------------------------------------
__global__ __launch_bounds__(256) void path_base(const float* __restrict__ QT,
                                                 const float* __restrict__ ident,
                                                 float* __restrict__ P) {
    __shared__ __align__(16) float vs[2][4][HALF];
    const int t    = threadIdx.x;
    const int rg   = t >> 6;                 // row in block (0..3), one wave each
    const int jj   = (t & 63) << 1;          // 2-col chunk
    const int v    = (blockIdx.x << 2) + rg;
    const int vmax = (blockIdx.x << 2) + 3;

    float2 cv = *(const float2*)&ident[jj];
    *(float2*)&vs[0][rg][jj] = cv;
    __syncthreads();

    int cur = 0;
    for (int d = 0; d < 8; ++d) {
        if ((vmax >> (d + 1)) == 0) break;           // block-uniform
        const bool valid = (v >> (d + 1)) > 0;
        const float* __restrict__ Qm = QT + (((v >> d) & 1) ? NMAT : 0);
        float2 acc = make_float2(0.f, 0.f);
        #pragma unroll 4
        for (int cc = 0; cc < 128; cc += 4) {
            float4 v4 = *(const float4*)&vs[cur][rg][cc];
            float2 q0 = *(const float2*)&Qm[(cc+0)*HALF + jj];
            float2 q1 = *(const float2*)&Qm[(cc+1)*HALF + jj];
            float2 q2 = *(const float2*)&Qm[(cc+2)*HALF + jj];
            float2 q3 = *(const float2*)&Qm[(cc+3)*HALF + jj];
            acc.x = fmaf(v4.x,q0.x, fmaf(v4.y,q1.x, fmaf(v4.z,q2.x, fmaf(v4.w,q3.x, acc.x))));
            acc.y = fmaf(v4.x,q0.y, fmaf(v4.y,q1.y, fmaf(v4.z,q2.y, fmaf(v4.w,q3.y, acc.y))));
        }
        if (valid) cv = acc;
        *(float2*)&vs[cur ^ 1][rg][jj] = cv;
        __syncthreads();
        cur ^= 1;
    }
    *(float2*)&P[v * HALF + jj] = cv;
}

// ---------------------------------------------------------------------------
// K2b: rows [256,4096), k-grouped, column-parallel, 256 threads.
// ROUND-4 VERIFIED FORM.
// ---------------------------------------------------------------------------
__global__ __launch_bounds__(256) void path_upper(const float* __restrict__ QT,
                                                  float* __restrict__ P) {
    __shared__ __align__(16) float vs[2][8][HALF];   // double-buffered row vals
    const int t  = threadIdx.x;
    const int j  = t & 127;                // owned output column
    const int h  = t >> 7;                 // row half: rows h*4 .. h*4+3
    const int k  = 2 + (blockIdx.x >> 4);  // 30 k-values x 16 blocks = 480
    const int r0 = (blockIdx.x & 15) << 3; // 8 residues per block

    float acc[4];
    #pragma unroll
    for (int rr = 0; rr < 4; ++rr)
        acc[rr] = P[(128 + r0 + h * 4 + rr) * HALF + j];

    int p = 0;
    for (int d = 7; d < 13; ++d) {
        if ((k >> (d - 6)) == 0) break;              // block-uniform
        const float* __restrict__ Qm = QT + (((k >> (d - 7)) & 1) ? NMAT : 0);
        #pragma unroll
        for (int rr = 0; rr < 4; ++rr) vs[p][h * 4 + rr][j] = acc[rr];
        __syncthreads();                             // other buffer still live

        float nacc[4] = {0.f, 0.f, 0.f, 0.f};
        #pragma unroll 4
        for (int cc = 0; cc < 128; cc += 4) {
            float q0 = Qm[(cc + 0) * HALF + j];      // coalesced global dword
            float q1 = Qm[(cc + 1) * HALF + j];
            float q2 = Qm[(cc + 2) * HALF + j];
            float q3 = Qm[(cc + 3) * HALF + j];
            #pragma unroll
            for (int rr = 0; rr < 4; ++rr) {
                float4 v4 = *(const float4*)&vs[p][h * 4 + rr][cc];  // broadcast
                nacc[rr] = fmaf(v4.x, q0,
                           fmaf(v4.y, q1,
                           fmaf(v4.z, q2,
                           fmaf(v4.w, q3, nacc[rr]))));
            }
        }
        #pragma unroll
        for (int rr = 0; rr < 4; ++rr) acc[rr] = nacc[rr];
        p ^= 1;                                      // next step: other buffer
    }

    #pragma unroll
    for (int rr = 0; rr < 4; ++rr)
        P[((k << 7) | (r0 + h * 4 + rr)) * HALF + j] = acc[rr];
}

// ---------------------------------------------------------------------------
// K3: emit [B,S,256] = content ++ pos.  ROUND-2 VERIFIED FORM (NT stores).
// ---------------------------------------------------------------------------
__global__ __launch_bounds__(256) void emit_out(const int* __restrict__ tt,
                                                const int* __restrict__ tv,
                                                const int* __restrict__ np,
                                                const float* __restrict__ P,
                                                const float* __restrict__ emb,
                                                float* __restrict__ out) {
    const int i  = (blockIdx.x << 2) + (threadIdx.x >> 6);
    const int jj = (threadIdx.x & 63) << 2;
    const int ty = tt[i];
    const int v  = tv[i];
    f4 val;
    if (jj < 128) {
        if (ty == 0)      val = *(const f4*)&emb[jj];
        else if (ty == 1) val = *(const f4*)&emb[(v + 1) * HALF + jj];
        else if (ty == 2) val = *(const f4*)&emb[(v + 5) * HALF + jj];
        else if (ty == 4) {
            int vc = v < 0 ? 0 : (v > 4095 ? 4095 : v);
            val = *(const f4*)&P[vc * HALF + jj];
        } else if (v == -1) val = *(const f4*)&emb[10 * HALF + jj];
        else { f4 z = {0.f, 0.f, 0.f, 0.f}; val = z; }
    } else {
        const int p = np[i];
        val = *(const f4*)&P[p * HALF + (jj - 128)];
    }
    __builtin_nontemporal_store(val, (f4*)&out[i * 256 + jj]);
}

extern "C" void kernel_launch(void* const* d_in, const int* in_sizes, int n_in,
                              void* d_out, int out_size, void* d_ws, size_t ws_size,
                              hipStream_t stream) {
    const int*   token_types = (const int*)  d_in[0];
    const int*   token_vals  = (const int*)  d_in[1];
    const int*   node_pos    = (const int*)  d_in[2];
    const float* prim        = (const float*)d_in[3];
    const float* ident       = (const float*)d_in[4];
    const float* emb         = (const float*)d_in[5];
    float* out = (float*)d_out;

    // workspace: QT[2][128][128] at 0 | P[4096][128] at 262144.
    // K1's ping-pong W buffers live in the first 256 KB of the P region --
    // P is written only after K1 completes (stream-ordered), so no conflict.
    float* QT = (float*)d_ws;
    float* P  = (float*)((char*)d_ws + 262144);
    float* W0 = (float*)((char*)d_ws + 262144);
    float* W1 = (float*)((char*)d_ws + 262144 + 131072);

    k1_2step<0, true,  false><<<16, 256, 0, stream>>>(prim, W0, W0);  // N -> post-1
    k1_2step<2, false, false><<<16, 256, 0, stream>>>(prim, W0, W1);  // -> post-3
    k1_2step<4, false, false><<<16, 256, 0, stream>>>(prim, W1, W0);  // -> post-5
    k1_2step<6, false, true ><<<16, 256, 0, stream>>>(prim, W0, QT);  // -> 2W-I

    path_base  <<<64,  256, 0, stream>>>(QT, ident, P);     // rows [0,256)
    path_upper <<<480, 256, 0, stream>>>(QT, P);            // rows [256,4096)
    emit_out   <<<NTOK / 4, 256, 0, stream>>>(token_types, token_vals, node_pos,
                                              P, emb, out);
}